// Round 7
// baseline (134.513 us; speedup 1.0000x reference)
//
#include <hip/hip_runtime.h>
#include <hip/hip_bf16.h>

// TripletLoss, N=8192, D=256 fp32, targets in [0,128).
// out[0] = mean(relu(dist_ap - dist_an + 0.3)), out[1] = mean(dist_an > dist_ap)
// dist = sqrt(clip(si + sj - 2 dot, 1e-12)).
//
// R6: CLASS-SORT the rows (rank-sort inside prep, one dispatch). After sorting,
// same-class pairs exist only where a wave's row-class range overlaps its
// col-class range (~3% of waves). Fast path = maskless min-reductions on
// key = sqB_j - 2*dot (B=65536 bias keeps keys positive for uint atomicMin;
// si-add and 1e-12 clip deferred to finish; reductions commute with monotone
// shifts). Slow path = old masked path in key space. Means are permutation-
// invariant, so no un-permute needed.
// K-loop: R4/R6 single-barrier double-buffered lds-DMA (proven -12% vs R2).
// NO __threadfence anywhere (R5 lesson: it wipes per-XCD L2 -> 3x).

#define N 8192
#define D 256
#define MARGIN 0.3f
#define NBLK 2080   // 64*65/2 lower-triangle 128x128 tiles
#define BIAS 65536.0f

typedef __bf16  bf16x8  __attribute__((ext_vector_type(8)));
typedef float   floatx4 __attribute__((ext_vector_type(4)));

__device__ __forceinline__ void load_lds16(const void* g, void* s) {
  __builtin_amdgcn_global_load_lds(
      (const __attribute__((address_space(1))) void*)g,
      (__attribute__((address_space(3))) void*)s, 16, 0, 0);
}

// ---- Kernel A: rank-sort by class + bf16 cast + biased sq-norms + init ------
// 1024 blocks x 256 threads; each wave ranks+moves 2 rows.
__global__ __launch_bounds__(256) void prep_kernel(
    const float* __restrict__ X, const int* __restrict__ tgt,
    unsigned short* __restrict__ Xb, float* __restrict__ sqB,
    int* __restrict__ tgtP, unsigned* __restrict__ pmax, unsigned* __restrict__ nmin) {
  __shared__ int keys[N];  // 32 KB: key = cls*16384 + j (lexicographic rank)
  const int t = threadIdx.x;
  const int lane = t & 63, wave = t >> 6;
#pragma unroll
  for (int u = 0; u < 32; ++u) {
    int j = u * 256 + t;
    keys[j] = tgt[j] * 16384 + j;
  }
  __syncthreads();
  const int row0 = blockIdx.x * 8 + wave * 2;
#pragma unroll
  for (int r = 0; r < 2; ++r) {
    const int row = row0 + r;
    const int Ki = keys[row];
    int cnt = 0;
#pragma unroll 4
    for (int u = 0; u < 32; ++u) {
      int4 k4 = *reinterpret_cast<const int4*>(&keys[u * 256 + lane * 4]);
      cnt += (k4.x < Ki) + (k4.y < Ki) + (k4.z < Ki) + (k4.w < Ki);
    }
#pragma unroll
    for (int o = 1; o < 64; o <<= 1) cnt += __shfl_xor(cnt, o);
    // cnt == sorted position (uniform across lanes)
    float4 v = *reinterpret_cast<const float4*>(X + (size_t)row * D + lane * 4);
    ushort4 h;
    {
      __hip_bfloat16 b0 = __float2bfloat16(v.x), b1 = __float2bfloat16(v.y);
      __hip_bfloat16 b2 = __float2bfloat16(v.z), b3 = __float2bfloat16(v.w);
      h.x = *reinterpret_cast<unsigned short*>(&b0);
      h.y = *reinterpret_cast<unsigned short*>(&b1);
      h.z = *reinterpret_cast<unsigned short*>(&b2);
      h.w = *reinterpret_cast<unsigned short*>(&b3);
    }
    *reinterpret_cast<ushort4*>(Xb + (size_t)cnt * D + lane * 4) = h;
    float s = v.x * v.x + v.y * v.y + v.z * v.z + v.w * v.w;
#pragma unroll
    for (int o = 32; o > 0; o >>= 1) s += __shfl_down(s, o);
    if (lane == 0) {
      sqB[cnt]  = s + BIAS;
      tgtP[cnt] = Ki >> 14;
      pmax[row] = 0u;            // identity for max of positive keys
      nmin[row] = 0x7F800000u;   // +inf
    }
  }
}

// ---- Kernel B: triangular tiles, dbuf LDS, sorted-class epilogue ------------
__global__ __launch_bounds__(256) void tile_kernel(
    const unsigned short* __restrict__ Xb, const float* __restrict__ sqB,
    const int* __restrict__ tgtP, unsigned* __restrict__ pmax, unsigned* __restrict__ nmin) {
  const int bi = blockIdx.x;
  int by = (int)((sqrtf(8.0f * (float)bi + 1.0f) - 1.0f) * 0.5f);
  while ((by + 1) * (by + 2) / 2 <= bi) ++by;
  while (by * (by + 1) / 2 > bi) --by;
  const int bx = bi - by * (by + 1) / 2;
  const int rowBase = by * 128, colBase = bx * 128;

  const int t = threadIdx.x;
  const int lane = t & 63, wave = t >> 6;
  const int wy = wave >> 1, wx = wave & 1;
  const int quad = lane >> 4, l15 = lane & 15;

  __shared__ __align__(16) unsigned short As[2][128 * 32];
  __shared__ __align__(16) unsigned short Bs[2][128 * 32];
  __shared__ float sqr[128], sqc[128];
  __shared__ int   tr[128], tc[128];
  __shared__ unsigned pmL[128], nmL[128], pmLc[128], nmLc[128];
  __shared__ int anyPos;

  if (t == 0) anyPos = 0;
  if (t < 128) {
    sqr[t] = sqB[rowBase + t]; tr[t] = tgtP[rowBase + t];
    pmL[t] = 0u; nmL[t] = 0x7F800000u;
  } else {
    int u = t - 128;
    sqc[u] = sqB[colBase + u]; tc[u] = tgtP[colBase + u];
    pmLc[u] = 0u; nmLc[u] = 0x7F800000u;
  }

  const unsigned short* Ag = Xb + (size_t)rowBase * D;
  const unsigned short* Bg = Xb + (size_t)colBase * D;

  int goff[2], lbase[2];
#pragma unroll
  for (int it = 0; it < 2; ++it) {
    int p = t + it * 256;
    int row = p >> 2;
    int c = (p & 3) ^ (row & 3);
    goff[it] = row * D + c * 8;
    lbase[it] = (it * 256 + wave * 64) * 16;
  }
  int aAddr[4], bAddr[4];
#pragma unroll
  for (int mi = 0; mi < 4; ++mi) {
    int row = wy * 64 + mi * 16 + l15;
    aAddr[mi] = (row * 4 + (quad ^ (row & 3))) * 16;
  }
#pragma unroll
  for (int nj = 0; nj < 4; ++nj) {
    int col = wx * 64 + nj * 16 + l15;
    bAddr[nj] = (col * 4 + (quad ^ (col & 3))) * 16;
  }

#pragma unroll
  for (int it = 0; it < 2; ++it) {
    load_lds16(Ag + goff[it], (char*)As[0] + lbase[it]);
    load_lds16(Bg + goff[it], (char*)Bs[0] + lbase[it]);
  }

  floatx4 acc[4][4];
#pragma unroll
  for (int mi = 0; mi < 4; ++mi)
#pragma unroll
    for (int nj = 0; nj < 4; ++nj)
      acc[mi][nj] = (floatx4){0.f, 0.f, 0.f, 0.f};

  for (int kk = 0; kk < 8; ++kk) {
    __syncthreads();  // drains buf[kk]'s DMA (issued one compute phase ago)
    if (kk < 7) {
      int k0n = (kk + 1) * 32;
      char* an = (char*)As[(kk + 1) & 1];
      char* bn = (char*)Bs[(kk + 1) & 1];
#pragma unroll
      for (int it = 0; it < 2; ++it) {
        load_lds16(Ag + goff[it] + k0n, an + lbase[it]);
        load_lds16(Bg + goff[it] + k0n, bn + lbase[it]);
      }
    }
    const char* abuf = (const char*)As[kk & 1];
    const char* bbuf = (const char*)Bs[kk & 1];
    bf16x8 a[4], b[4];
#pragma unroll
    for (int mi = 0; mi < 4; ++mi)
      a[mi] = *reinterpret_cast<const bf16x8*>(abuf + aAddr[mi]);
#pragma unroll
    for (int nj = 0; nj < 4; ++nj)
      b[nj] = *reinterpret_cast<const bf16x8*>(bbuf + bAddr[nj]);
#pragma unroll
    for (int mi = 0; mi < 4; ++mi)
#pragma unroll
      for (int nj = 0; nj < 4; ++nj)
        acc[mi][nj] = __builtin_amdgcn_mfma_f32_16x16x32_bf16(a[mi], b[nj], acc[mi][nj], 0, 0, 0);
  }

  // ---- epilogue in key space: rowkey = sqB_j - 2dot, colkey = sqB_i - 2dot --
  float sqcB_l[4]; int tc_l[4];
#pragma unroll
  for (int nj = 0; nj < 4; ++nj) {
    int jl = wx * 64 + nj * 16 + l15;
    sqcB_l[nj] = sqc[jl];
    tc_l[nj]   = tc[jl];
  }
  // sorted classes: wave's row/col class ranges from endpoints
  const int rlo = tr[wy * 64], rhi = tr[wy * 64 + 63];
  const int clo = tc[wx * 64], chi = tc[wx * 64 + 63];
  const bool havePos = (rhi >= clo) && (chi >= rlo);

  float nm[16], cmN[4];
#pragma unroll
  for (int s = 0; s < 16; ++s) nm[s] = __builtin_huge_valf();
#pragma unroll
  for (int nj = 0; nj < 4; ++nj) cmN[nj] = __builtin_huge_valf();

  if (!havePos) {
    // fast path (~97% of waves): no same-class pairs -> maskless min only
#pragma unroll
    for (int mi = 0; mi < 4; ++mi) {
#pragma unroll
      for (int r = 0; r < 4; ++r) {
        float siB = sqr[wy * 64 + mi * 16 + quad * 4 + r];
        int s = mi * 4 + r;
#pragma unroll
        for (int nj = 0; nj < 4; ++nj) {
          float dot = acc[mi][nj][r];
          nm[s]   = fminf(nm[s],   fmaf(-2.f, dot, sqcB_l[nj]));
          cmN[nj] = fminf(cmN[nj], fmaf(-2.f, dot, siB));
        }
      }
    }
  } else {
    if (lane == 0) anyPos = 1;
    float pm[16], cmP[4];
#pragma unroll
    for (int s = 0; s < 16; ++s) pm[s] = 0.f;
#pragma unroll
    for (int nj = 0; nj < 4; ++nj) cmP[nj] = 0.f;
#pragma unroll
    for (int mi = 0; mi < 4; ++mi) {
#pragma unroll
      for (int r = 0; r < 4; ++r) {
        int il = wy * 64 + mi * 16 + quad * 4 + r;
        float siB = sqr[il];
        int   ti  = tr[il];
        int   s   = mi * 4 + r;
#pragma unroll
        for (int nj = 0; nj < 4; ++nj) {
          float dot = acc[mi][nj][r];
          float rk = fmaf(-2.f, dot, sqcB_l[nj]);
          float ck = fmaf(-2.f, dot, siB);
          bool same = (ti == tc_l[nj]);
          pm[s]   = fmaxf(pm[s],   same ? rk : 0.f);
          nm[s]   = fminf(nm[s],   same ? __builtin_huge_valf() : rk);
          cmP[nj] = fmaxf(cmP[nj], same ? ck : 0.f);
          cmN[nj] = fminf(cmN[nj], same ? __builtin_huge_valf() : ck);
        }
      }
    }
    // pm butterfly (slow-path waves only)
#pragma unroll
    for (int m = 8; m >= 1; m >>= 1) {
#pragma unroll
      for (int j = 0; j < m; ++j) {
        bool up = (l15 & m) != 0;
        float sp = up ? pm[j] : pm[j + m];
        float rp = __shfl_xor(sp, m);
        float kp = up ? pm[j + m] : pm[j];
        pm[j] = fmaxf(kp, rp);
      }
    }
    {
      int rowIdx = wy * 64 + ((l15 >> 2) << 4) + (quad << 2) + (l15 & 3);
      atomicMax(&pmL[rowIdx], __float_as_uint(pm[0]));
    }
#pragma unroll
    for (int nj = 0; nj < 4; ++nj) {
      cmP[nj] = fmaxf(cmP[nj], __shfl_xor(cmP[nj], 16));
      cmP[nj] = fmaxf(cmP[nj], __shfl_xor(cmP[nj], 32));
    }
    {
      float vP = (quad == 0) ? cmP[0] : (quad == 1) ? cmP[1] : (quad == 2) ? cmP[2] : cmP[3];
      atomicMax(&pmLc[wx * 64 + quad * 16 + l15], __float_as_uint(vP));
    }
  }

  // nm butterfly (all waves)
#pragma unroll
  for (int m = 8; m >= 1; m >>= 1) {
#pragma unroll
    for (int j = 0; j < m; ++j) {
      bool up = (l15 & m) != 0;
      float sn = up ? nm[j] : nm[j + m];
      float rn = __shfl_xor(sn, m);
      float kn = up ? nm[j + m] : nm[j];
      nm[j] = fminf(kn, rn);
    }
  }
  {
    int rowIdx = wy * 64 + ((l15 >> 2) << 4) + (quad << 2) + (l15 & 3);
    atomicMin(&nmL[rowIdx], __float_as_uint(nm[0]));
  }
#pragma unroll
  for (int nj = 0; nj < 4; ++nj) {
    cmN[nj] = fminf(cmN[nj], __shfl_xor(cmN[nj], 16));
    cmN[nj] = fminf(cmN[nj], __shfl_xor(cmN[nj], 32));
  }
  {
    float vN = (quad == 0) ? cmN[0] : (quad == 1) ? cmN[1] : (quad == 2) ? cmN[2] : cmN[3];
    atomicMin(&nmLc[wx * 64 + quad * 16 + l15], __float_as_uint(vN));
  }
  __syncthreads();

  if (t < 128) {
    if (anyPos) atomicMax(&pmax[rowBase + t], pmL[t]);
    atomicMin(&nmin[rowBase + t], nmL[t]);
  } else {
    int u = t - 128;
    if (anyPos) atomicMax(&pmax[colBase + u], pmLc[u]);
    atomicMin(&nmin[colBase + u], nmLc[u]);
  }
}

// ---- Kernel C: final loss/prec (1 block) ------------------------------------
__global__ __launch_bounds__(256) void finish_kernel(
    const unsigned* __restrict__ pmax, const unsigned* __restrict__ nmin,
    const float* __restrict__ sqB, float* __restrict__ out) {
  const int t = threadIdx.x;
  float lsum = 0.f, psum = 0.f;
  for (int i = t; i < N; i += 256) {
    float sq2 = sqB[i] - 2.0f * BIAS;  // si - B
    float ap2 = sq2 + __uint_as_float(pmax[i]);  // si + (pm - B)
    float an2 = sq2 + __uint_as_float(nmin[i]);
    float ap = sqrtf(fmaxf(ap2, 1e-12f));
    float an = sqrtf(fmaxf(an2, 1e-12f));
    lsum += fmaxf(ap - an + MARGIN, 0.f);
    psum += (an > ap) ? 1.f : 0.f;
  }
#pragma unroll
  for (int o = 32; o > 0; o >>= 1) {
    lsum += __shfl_down(lsum, o);
    psum += __shfl_down(psum, o);
  }
  __shared__ float ls[4], ps[4];
  if ((t & 63) == 0) { ls[t >> 6] = lsum; ps[t >> 6] = psum; }
  __syncthreads();
  if (t == 0) {
    out[0] = (ls[0] + ls[1] + ls[2] + ls[3]) * (1.0f / (float)N);
    out[1] = (ps[0] + ps[1] + ps[2] + ps[3]) * (1.0f / (float)N);
  }
}

extern "C" void kernel_launch(void* const* d_in, const int* in_sizes, int n_in,
                              void* d_out, int out_size, void* d_ws, size_t ws_size,
                              hipStream_t stream) {
  const float* X  = (const float*)d_in[0];
  const int* tgt  = (const int*)d_in[1];
  float* out      = (float*)d_out;

  char* ws = (char*)d_ws;
  unsigned short* Xb = (unsigned short*)ws;                    // 4 MiB (sorted)
  float*    sqB   = (float*)(ws + 4194304);                    // 32 KiB (si + B)
  int*      tgtP  = (int*)(ws + 4194304 + 32768);              // 32 KiB (sorted cls)
  unsigned* pmax  = (unsigned*)(ws + 4194304 + 65536);         // 32 KiB
  unsigned* nmin  = (unsigned*)(ws + 4194304 + 98304);         // 32 KiB

  prep_kernel<<<1024, 256, 0, stream>>>(X, tgt, Xb, sqB, tgtP, pmax, nmin);
  tile_kernel<<<NBLK, 256, 0, stream>>>(Xb, sqB, tgtP, pmax, nmin);
  finish_kernel<<<1, 256, 0, stream>>>(pmax, nmin, sqB, out);
}

// Round 8
// 129.423 us; speedup vs baseline: 1.0393x; 1.0393x over previous
//
#include <hip/hip_runtime.h>
#include <hip/hip_bf16.h>

// TripletLoss, N=8192, D=256 fp32, targets in [0,128).
// out[0]=mean(relu(dist_ap-dist_an+0.3)), out[1]=mean(dist_an>dist_ap)
// dist=sqrt(clip(si+sj-2dot,1e-12)); clip/sqrt deferred (monotone).
// All reductions in KEY SPACE: key = B + s_other - 2dot (B=65536 keeps keys
// positive -> uint order == float order for atomicMax/Min); finish adds s_i-B.
//
// R7: fast/slow SPLIT KERNELS. R6 lesson: waves/SIMD = 512/(VGPR+AGPR);
// in-kernel branch unioned registers (84->128 arch VGPR, 3->2 waves, -13%).
// Separate kernels keep the maskless fast path lean. Classification: sorted
// classes -> overlap test on 4 uniform endpoint loads, uniform early-exit.
// ~127/2080 blocks slow (all diagonals + class-boundary straddlers).
// K-loop: proven single-barrier dbuf lds-DMA. NO __threadfence (R5: L2 wipe).

#define N 8192
#define D 256
#define MARGIN 0.3f
#define NBLK 2080   // 64*65/2 lower-triangle 128x128 tiles
#define BIAS 65536.0f

typedef __bf16  bf16x8  __attribute__((ext_vector_type(8)));
typedef float   floatx4 __attribute__((ext_vector_type(4)));

__device__ __forceinline__ void load_lds16(const void* g, void* s) {
  __builtin_amdgcn_global_load_lds(
      (const __attribute__((address_space(1))) void*)g,
      (__attribute__((address_space(3))) void*)s, 16, 0, 0);
}

__device__ __forceinline__ void tri_decode(int bi, int& by, int& bx) {
  by = (int)((sqrtf(8.0f * (float)bi + 1.0f) - 1.0f) * 0.5f);
  while ((by + 1) * (by + 2) / 2 <= bi) ++by;
  while (by * (by + 1) / 2 > bi) --by;
  bx = bi - by * (by + 1) / 2;
}

// ---- Kernel A: rank-sort by class + bf16 cast + biased sq-norms + init ------
__global__ __launch_bounds__(256) void prep_kernel(
    const float* __restrict__ X, const int* __restrict__ tgt,
    unsigned short* __restrict__ Xb, float* __restrict__ sqB,
    int* __restrict__ tgtP, unsigned* __restrict__ pmax, unsigned* __restrict__ nmin) {
  __shared__ int keys[N];  // 32 KB: key = cls*16384 + j (lexicographic rank)
  const int t = threadIdx.x;
  const int lane = t & 63, wave = t >> 6;
#pragma unroll
  for (int u = 0; u < 32; ++u) {
    int j = u * 256 + t;
    keys[j] = tgt[j] * 16384 + j;
  }
  __syncthreads();
  const int row0 = blockIdx.x * 8 + wave * 2;
#pragma unroll
  for (int r = 0; r < 2; ++r) {
    const int row = row0 + r;
    const int Ki = keys[row];
    int cnt = 0;
#pragma unroll 4
    for (int u = 0; u < 32; ++u) {
      int4 k4 = *reinterpret_cast<const int4*>(&keys[u * 256 + lane * 4]);
      cnt += (k4.x < Ki) + (k4.y < Ki) + (k4.z < Ki) + (k4.w < Ki);
    }
#pragma unroll
    for (int o = 1; o < 64; o <<= 1) cnt += __shfl_xor(cnt, o);
    // cnt == sorted position (uniform across lanes)
    float4 v = *reinterpret_cast<const float4*>(X + (size_t)row * D + lane * 4);
    ushort4 h;
    {
      __hip_bfloat16 b0 = __float2bfloat16(v.x), b1 = __float2bfloat16(v.y);
      __hip_bfloat16 b2 = __float2bfloat16(v.z), b3 = __float2bfloat16(v.w);
      h.x = *reinterpret_cast<unsigned short*>(&b0);
      h.y = *reinterpret_cast<unsigned short*>(&b1);
      h.z = *reinterpret_cast<unsigned short*>(&b2);
      h.w = *reinterpret_cast<unsigned short*>(&b3);
    }
    *reinterpret_cast<ushort4*>(Xb + (size_t)cnt * D + lane * 4) = h;
    float s = v.x * v.x + v.y * v.y + v.z * v.z + v.w * v.w;
#pragma unroll
    for (int o = 32; o > 0; o >>= 1) s += __shfl_down(s, o);
    if (lane == 0) {
      sqB[cnt]  = s + BIAS;
      tgtP[cnt] = Ki >> 14;
      pmax[row] = 0u;            // identity for max of positive keys
      nmin[row] = 0x7F800000u;   // +inf
    }
  }
}

// ---- Kernel B1: FAST tiles (no same-class pairs) — maskless min only --------
__global__ __launch_bounds__(256) void tile_fast(
    const unsigned short* __restrict__ Xb, const float* __restrict__ sqB,
    const int* __restrict__ tgtP, unsigned* __restrict__ nmin) {
  int by, bx; tri_decode(blockIdx.x, by, bx);
  const int rowBase = by * 128, colBase = bx * 128;
  // sorted-class overlap test (uniform scalar loads) — overlap -> slow kernel
  if (tgtP[rowBase + 127] >= tgtP[colBase] && tgtP[colBase + 127] >= tgtP[rowBase])
    return;

  const int t = threadIdx.x;
  const int lane = t & 63, wave = t >> 6;
  const int wy = wave >> 1, wx = wave & 1;
  const int quad = lane >> 4, l15 = lane & 15;

  __shared__ __align__(16) unsigned short As[2][128 * 32];
  __shared__ __align__(16) unsigned short Bs[2][128 * 32];
  __shared__ float sqr[128], sqc[128];
  __shared__ unsigned nmL[128], nmLc[128];

  if (t < 128) { sqr[t] = sqB[rowBase + t]; nmL[t] = 0x7F800000u; }
  else { int u = t - 128; sqc[u] = sqB[colBase + u]; nmLc[u] = 0x7F800000u; }

  const unsigned short* Ag = Xb + (size_t)rowBase * D;
  const unsigned short* Bg = Xb + (size_t)colBase * D;

  int goff[2], lbase[2];
#pragma unroll
  for (int it = 0; it < 2; ++it) {
    int p = t + it * 256;
    int row = p >> 2;
    int c = (p & 3) ^ (row & 3);
    goff[it] = row * D + c * 8;
    lbase[it] = (it * 256 + wave * 64) * 16;
  }
  int aAddr[4], bAddr[4];
#pragma unroll
  for (int mi = 0; mi < 4; ++mi) {
    int row = wy * 64 + mi * 16 + l15;
    aAddr[mi] = (row * 4 + (quad ^ (row & 3))) * 16;
  }
#pragma unroll
  for (int nj = 0; nj < 4; ++nj) {
    int col = wx * 64 + nj * 16 + l15;
    bAddr[nj] = (col * 4 + (quad ^ (col & 3))) * 16;
  }

#pragma unroll
  for (int it = 0; it < 2; ++it) {
    load_lds16(Ag + goff[it], (char*)As[0] + lbase[it]);
    load_lds16(Bg + goff[it], (char*)Bs[0] + lbase[it]);
  }

  floatx4 acc[4][4];
#pragma unroll
  for (int mi = 0; mi < 4; ++mi)
#pragma unroll
    for (int nj = 0; nj < 4; ++nj)
      acc[mi][nj] = (floatx4){0.f, 0.f, 0.f, 0.f};

  for (int kk = 0; kk < 8; ++kk) {
    __syncthreads();
    if (kk < 7) {
      int k0n = (kk + 1) * 32;
      char* an = (char*)As[(kk + 1) & 1];
      char* bn = (char*)Bs[(kk + 1) & 1];
#pragma unroll
      for (int it = 0; it < 2; ++it) {
        load_lds16(Ag + goff[it] + k0n, an + lbase[it]);
        load_lds16(Bg + goff[it] + k0n, bn + lbase[it]);
      }
    }
    const char* abuf = (const char*)As[kk & 1];
    const char* bbuf = (const char*)Bs[kk & 1];
    bf16x8 a[4], b[4];
#pragma unroll
    for (int mi = 0; mi < 4; ++mi)
      a[mi] = *reinterpret_cast<const bf16x8*>(abuf + aAddr[mi]);
#pragma unroll
    for (int nj = 0; nj < 4; ++nj)
      b[nj] = *reinterpret_cast<const bf16x8*>(bbuf + bAddr[nj]);
#pragma unroll
    for (int mi = 0; mi < 4; ++mi)
#pragma unroll
      for (int nj = 0; nj < 4; ++nj)
        acc[mi][nj] = __builtin_amdgcn_mfma_f32_16x16x32_bf16(a[mi], b[nj], acc[mi][nj], 0, 0, 0);
  }

  // maskless epilogue: rowkey = sqB_col - 2dot (-> nmL), colkey = sqB_row - 2dot
  float sqcB_l[4];
#pragma unroll
  for (int nj = 0; nj < 4; ++nj) sqcB_l[nj] = sqc[wx * 64 + nj * 16 + l15];

  float nm[16], cmN[4];
#pragma unroll
  for (int s = 0; s < 16; ++s) nm[s] = __builtin_huge_valf();
#pragma unroll
  for (int nj = 0; nj < 4; ++nj) cmN[nj] = __builtin_huge_valf();

#pragma unroll
  for (int mi = 0; mi < 4; ++mi) {
    floatx4 siB4 = *reinterpret_cast<const floatx4*>(&sqr[wy * 64 + mi * 16 + quad * 4]);
#pragma unroll
    for (int r = 0; r < 4; ++r) {
      float siB = siB4[r];
      int s = mi * 4 + r;
#pragma unroll
      for (int nj = 0; nj < 4; ++nj) {
        float dot = acc[mi][nj][r];
        nm[s]   = fminf(nm[s],   fmaf(-2.f, dot, sqcB_l[nj]));
        cmN[nj] = fminf(cmN[nj], fmaf(-2.f, dot, siB));
      }
    }
  }

  // nm halving butterfly across 16 lanes of each quad group
#pragma unroll
  for (int m = 8; m >= 1; m >>= 1) {
#pragma unroll
    for (int j = 0; j < m; ++j) {
      bool up = (l15 & m) != 0;
      float sn = up ? nm[j] : nm[j + m];
      float rn = __shfl_xor(sn, m);
      float kn = up ? nm[j + m] : nm[j];
      nm[j] = fminf(kn, rn);
    }
  }
  {
    int rowIdx = wy * 64 + ((l15 >> 2) << 4) + (quad << 2) + (l15 & 3);
    atomicMin(&nmL[rowIdx], __float_as_uint(nm[0]));
  }
#pragma unroll
  for (int nj = 0; nj < 4; ++nj) {
    cmN[nj] = fminf(cmN[nj], __shfl_xor(cmN[nj], 16));
    cmN[nj] = fminf(cmN[nj], __shfl_xor(cmN[nj], 32));
  }
  {
    float vN = (quad == 0) ? cmN[0] : (quad == 1) ? cmN[1] : (quad == 2) ? cmN[2] : cmN[3];
    atomicMin(&nmLc[wx * 64 + quad * 16 + l15], __float_as_uint(vN));
  }
  __syncthreads();

  if (t < 128) atomicMin(&nmin[rowBase + t], nmL[t]);
  else { int u = t - 128; atomicMin(&nmin[colBase + u], nmLc[u]); }
}

// ---- Kernel B2: SLOW tiles (class overlap) — masked, key space --------------
__global__ __launch_bounds__(256) void tile_slow(
    const unsigned short* __restrict__ Xb, const float* __restrict__ sqB,
    const int* __restrict__ tgtP, unsigned* __restrict__ pmax, unsigned* __restrict__ nmin) {
  int by, bx; tri_decode(blockIdx.x, by, bx);
  const int rowBase = by * 128, colBase = bx * 128;
  if (!(tgtP[rowBase + 127] >= tgtP[colBase] && tgtP[colBase + 127] >= tgtP[rowBase]))
    return;

  const int t = threadIdx.x;
  const int lane = t & 63, wave = t >> 6;
  const int wy = wave >> 1, wx = wave & 1;
  const int quad = lane >> 4, l15 = lane & 15;

  __shared__ __align__(16) unsigned short As[2][128 * 32];
  __shared__ __align__(16) unsigned short Bs[2][128 * 32];
  __shared__ float sqr[128], sqc[128];
  __shared__ int   tr[128], tc[128];
  __shared__ unsigned pmL[128], nmL[128], pmLc[128], nmLc[128];

  if (t < 128) {
    sqr[t] = sqB[rowBase + t]; tr[t] = tgtP[rowBase + t];
    pmL[t] = 0u; nmL[t] = 0x7F800000u;
  } else {
    int u = t - 128;
    sqc[u] = sqB[colBase + u]; tc[u] = tgtP[colBase + u];
    pmLc[u] = 0u; nmLc[u] = 0x7F800000u;
  }

  const unsigned short* Ag = Xb + (size_t)rowBase * D;
  const unsigned short* Bg = Xb + (size_t)colBase * D;

  int goff[2], lbase[2];
#pragma unroll
  for (int it = 0; it < 2; ++it) {
    int p = t + it * 256;
    int row = p >> 2;
    int c = (p & 3) ^ (row & 3);
    goff[it] = row * D + c * 8;
    lbase[it] = (it * 256 + wave * 64) * 16;
  }
  int aAddr[4], bAddr[4];
#pragma unroll
  for (int mi = 0; mi < 4; ++mi) {
    int row = wy * 64 + mi * 16 + l15;
    aAddr[mi] = (row * 4 + (quad ^ (row & 3))) * 16;
  }
#pragma unroll
  for (int nj = 0; nj < 4; ++nj) {
    int col = wx * 64 + nj * 16 + l15;
    bAddr[nj] = (col * 4 + (quad ^ (col & 3))) * 16;
  }

#pragma unroll
  for (int it = 0; it < 2; ++it) {
    load_lds16(Ag + goff[it], (char*)As[0] + lbase[it]);
    load_lds16(Bg + goff[it], (char*)Bs[0] + lbase[it]);
  }

  floatx4 acc[4][4];
#pragma unroll
  for (int mi = 0; mi < 4; ++mi)
#pragma unroll
    for (int nj = 0; nj < 4; ++nj)
      acc[mi][nj] = (floatx4){0.f, 0.f, 0.f, 0.f};

  for (int kk = 0; kk < 8; ++kk) {
    __syncthreads();
    if (kk < 7) {
      int k0n = (kk + 1) * 32;
      char* an = (char*)As[(kk + 1) & 1];
      char* bn = (char*)Bs[(kk + 1) & 1];
#pragma unroll
      for (int it = 0; it < 2; ++it) {
        load_lds16(Ag + goff[it] + k0n, an + lbase[it]);
        load_lds16(Bg + goff[it] + k0n, bn + lbase[it]);
      }
    }
    const char* abuf = (const char*)As[kk & 1];
    const char* bbuf = (const char*)Bs[kk & 1];
    bf16x8 a[4], b[4];
#pragma unroll
    for (int mi = 0; mi < 4; ++mi)
      a[mi] = *reinterpret_cast<const bf16x8*>(abuf + aAddr[mi]);
#pragma unroll
    for (int nj = 0; nj < 4; ++nj)
      b[nj] = *reinterpret_cast<const bf16x8*>(bbuf + bAddr[nj]);
#pragma unroll
    for (int mi = 0; mi < 4; ++mi)
#pragma unroll
      for (int nj = 0; nj < 4; ++nj)
        acc[mi][nj] = __builtin_amdgcn_mfma_f32_16x16x32_bf16(a[mi], b[nj], acc[mi][nj], 0, 0, 0);
  }

  // masked epilogue in key space
  float sqcB_l[4]; int tc_l[4];
#pragma unroll
  for (int nj = 0; nj < 4; ++nj) {
    int jl = wx * 64 + nj * 16 + l15;
    sqcB_l[nj] = sqc[jl];
    tc_l[nj]   = tc[jl];
  }

  float pm[16], nm[16], cmP[4], cmN[4];
#pragma unroll
  for (int s = 0; s < 16; ++s) { pm[s] = 0.f; nm[s] = __builtin_huge_valf(); }
#pragma unroll
  for (int nj = 0; nj < 4; ++nj) { cmP[nj] = 0.f; cmN[nj] = __builtin_huge_valf(); }

#pragma unroll
  for (int mi = 0; mi < 4; ++mi) {
#pragma unroll
    for (int r = 0; r < 4; ++r) {
      int il = wy * 64 + mi * 16 + quad * 4 + r;
      float siB = sqr[il];
      int   ti  = tr[il];
      int   s   = mi * 4 + r;
#pragma unroll
      for (int nj = 0; nj < 4; ++nj) {
        float dot = acc[mi][nj][r];
        float rk = fmaf(-2.f, dot, sqcB_l[nj]);
        float ck = fmaf(-2.f, dot, siB);
        bool same = (ti == tc_l[nj]);
        pm[s]   = fmaxf(pm[s],   same ? rk : 0.f);
        nm[s]   = fminf(nm[s],   same ? __builtin_huge_valf() : rk);
        cmP[nj] = fmaxf(cmP[nj], same ? ck : 0.f);
        cmN[nj] = fminf(cmN[nj], same ? __builtin_huge_valf() : ck);
      }
    }
  }

#pragma unroll
  for (int m = 8; m >= 1; m >>= 1) {
#pragma unroll
    for (int j = 0; j < m; ++j) {
      bool up = (l15 & m) != 0;
      float sp = up ? pm[j] : pm[j + m];
      float sn = up ? nm[j] : nm[j + m];
      float rp = __shfl_xor(sp, m);
      float rn = __shfl_xor(sn, m);
      float kp = up ? pm[j + m] : pm[j];
      float kn = up ? nm[j + m] : nm[j];
      pm[j] = fmaxf(kp, rp);
      nm[j] = fminf(kn, rn);
    }
  }
  {
    int rowIdx = wy * 64 + ((l15 >> 2) << 4) + (quad << 2) + (l15 & 3);
    atomicMax(&pmL[rowIdx], __float_as_uint(pm[0]));
    atomicMin(&nmL[rowIdx], __float_as_uint(nm[0]));
  }
#pragma unroll
  for (int nj = 0; nj < 4; ++nj) {
    cmP[nj] = fmaxf(cmP[nj], __shfl_xor(cmP[nj], 16));
    cmP[nj] = fmaxf(cmP[nj], __shfl_xor(cmP[nj], 32));
    cmN[nj] = fminf(cmN[nj], __shfl_xor(cmN[nj], 16));
    cmN[nj] = fminf(cmN[nj], __shfl_xor(cmN[nj], 32));
  }
  {
    float vP = (quad == 0) ? cmP[0] : (quad == 1) ? cmP[1] : (quad == 2) ? cmP[2] : cmP[3];
    float vN = (quad == 0) ? cmN[0] : (quad == 1) ? cmN[1] : (quad == 2) ? cmN[2] : cmN[3];
    int colIdx = wx * 64 + quad * 16 + l15;
    atomicMax(&pmLc[colIdx], __float_as_uint(vP));
    atomicMin(&nmLc[colIdx], __float_as_uint(vN));
  }
  __syncthreads();

  if (t < 128) {
    atomicMax(&pmax[rowBase + t], pmL[t]);
    atomicMin(&nmin[rowBase + t], nmL[t]);
  } else {
    int u = t - 128;
    atomicMax(&pmax[colBase + u], pmLc[u]);
    atomicMin(&nmin[colBase + u], nmLc[u]);
  }
}

// ---- Kernel C: final loss/prec (1 block) ------------------------------------
__global__ __launch_bounds__(256) void finish_kernel(
    const unsigned* __restrict__ pmax, const unsigned* __restrict__ nmin,
    const float* __restrict__ sqB, float* __restrict__ out) {
  const int t = threadIdx.x;
  float lsum = 0.f, psum = 0.f;
  for (int i = t; i < N; i += 256) {
    float sq2 = sqB[i] - 2.0f * BIAS;  // s_i - B
    float ap2 = sq2 + __uint_as_float(pmax[i]);
    float an2 = sq2 + __uint_as_float(nmin[i]);
    float ap = sqrtf(fmaxf(ap2, 1e-12f));
    float an = sqrtf(fmaxf(an2, 1e-12f));
    lsum += fmaxf(ap - an + MARGIN, 0.f);
    psum += (an > ap) ? 1.f : 0.f;
  }
#pragma unroll
  for (int o = 32; o > 0; o >>= 1) {
    lsum += __shfl_down(lsum, o);
    psum += __shfl_down(psum, o);
  }
  __shared__ float ls[4], ps[4];
  if ((t & 63) == 0) { ls[t >> 6] = lsum; ps[t >> 6] = psum; }
  __syncthreads();
  if (t == 0) {
    out[0] = (ls[0] + ls[1] + ls[2] + ls[3]) * (1.0f / (float)N);
    out[1] = (ps[0] + ps[1] + ps[2] + ps[3]) * (1.0f / (float)N);
  }
}

extern "C" void kernel_launch(void* const* d_in, const int* in_sizes, int n_in,
                              void* d_out, int out_size, void* d_ws, size_t ws_size,
                              hipStream_t stream) {
  const float* X  = (const float*)d_in[0];
  const int* tgt  = (const int*)d_in[1];
  float* out      = (float*)d_out;

  char* ws = (char*)d_ws;
  unsigned short* Xb = (unsigned short*)ws;                    // 4 MiB (sorted)
  float*    sqB   = (float*)(ws + 4194304);                    // 32 KiB (s_i + B)
  int*      tgtP  = (int*)(ws + 4194304 + 32768);              // 32 KiB (sorted cls)
  unsigned* pmax  = (unsigned*)(ws + 4194304 + 65536);         // 32 KiB
  unsigned* nmin  = (unsigned*)(ws + 4194304 + 98304);         // 32 KiB

  prep_kernel<<<1024, 256, 0, stream>>>(X, tgt, Xb, sqB, tgtP, pmax, nmin);
  tile_fast<<<NBLK, 256, 0, stream>>>(Xb, sqB, tgtP, nmin);
  tile_slow<<<NBLK, 256, 0, stream>>>(Xb, sqB, tgtP, pmax, nmin);
  finish_kernel<<<1, 256, 0, stream>>>(pmax, nmin, sqB, out);
}